// Round 1
// 504.642 us; speedup vs baseline: 1.1112x; 1.1112x over previous
//
#include <hip/hip_runtime.h>

#define TPB 1024
#define NFFT 16384
#define LROW 8192
#define LDSN 17408  // 16384 + 16384/16 padded complex slots (136 KiB)

typedef float2 cpx;

// Padded LDS index: +1 slot per 16 complex. Injective, and ADDITIVE across
// the disjoint digit fields of every FFT round: pad(base + e*A + d*B) =
// pad-ish(base) + (A + A/16)*e + (B + B/16)*d when fields don't straddle
// bit 4 (verified for all rounds below). This lets every round use ONE base
// register + compile-time immediate offsets for all 32 LDS accesses.
__device__ __forceinline__ int pad(int p) { return p + (p >> 4); }

// reverse 7 base-4 digits (14 bits)
__device__ __forceinline__ int rev4_14(int p) {
  unsigned r = __brev((unsigned)p) >> 18;
  return (int)(((r & 0x1555u) << 1) | ((r & 0x2AAAu) >> 1));
}

// hardware sin/cos: input in REVOLUTIONS (v_sin_f32: D = sin(S0*2pi))
__device__ __forceinline__ void sc_rev(float rev, float& c, float& s) {
  s = __builtin_amdgcn_sinf(rev);
  c = __builtin_amdgcn_cosf(rev);
}

__device__ __forceinline__ cpx cmul(cpx a, float c, float s) {
  return make_float2(a.x * c - a.y * s, a.x * s + a.y * c);
}

#define C16 0.923879532511287f
#define S16 0.382683432365090f

// radix-4 DIF core (sign e^{-i}), in place
__device__ __forceinline__ void dif_core(cpx& a0, cpx& a1, cpx& a2, cpx& a3) {
  float t0r = a0.x + a2.x, t0i = a0.y + a2.y;
  float t1r = a0.x - a2.x, t1i = a0.y - a2.y;
  float t2r = a1.x + a3.x, t2i = a1.y + a3.y;
  float t3r = a1.x - a3.x, t3i = a1.y - a3.y;
  a0 = make_float2(t0r + t2r, t0i + t2i);
  a1 = make_float2(t1r + t3i, t1i - t3r);   // t1 - i*t3
  a2 = make_float2(t0r - t2r, t0i - t2i);
  a3 = make_float2(t1r - t3i, t1i + t3r);   // t1 + i*t3
}

// radix-4 DIT core (inputs pre-twiddled, sign e^{+i}), in place
__device__ __forceinline__ void dit_core(cpx& a0, cpx& a1, cpx& a2, cpx& a3) {
  float t0r = a0.x + a2.x, t0i = a0.y + a2.y;
  float t1r = a0.x - a2.x, t1i = a0.y - a2.y;
  float t2r = a1.x + a3.x, t2i = a1.y + a3.y;
  float t3r = a1.x - a3.x, t3i = a1.y - a3.y;
  a0 = make_float2(t0r + t2r, t0i + t2i);
  a1 = make_float2(t1r - t3i, t1i + t3r);   // t1 + i*t3
  a2 = make_float2(t0r - t2r, t0i - t2i);
  a3 = make_float2(t1r + t3i, t1i - t3r);   // t1 - i*t3
}

// ---- forward round A: global -> 2 stages in regs (n=16384, 4096) -> LDS ----
// store index p = t + 1024e + 4096d  ->  pad(p) = [t + (t>>4)] + 1088e + 4352d
__device__ __forceinline__ void fwd_first(const float* __restrict__ xr,
                                          const float* __restrict__ hr,
                                          cpx* __restrict__ z, int t) {
  cpx X[4][4];  // [e][d], p = t + 1024e + 4096d ; d=2,3 are the zero padding
  #pragma unroll
  for (int e = 0; e < 4; e++) {
    #pragma unroll
    for (int d = 0; d < 2; d++) {
      int p = t + 1024 * e + 4096 * d;
      X[e][d] = make_float2(xr[p], hr[p]);
    }
  }
  // stage n=16384 (q=4096): inputs d=2,3 zero => y0=a0+a1, y1=a0-i a1, y2=a0-a1, y3=a0+i a1
  float c1, s1;
  sc_rev(-(float)t * (1.0f / 16384.0f), c1, s1);
  #pragma unroll
  for (int e = 0; e < 4; e++) {
    if (e) {  // rotate by -2pi/16
      float tc = c1 * C16 + s1 * S16;
      float ts = s1 * C16 - c1 * S16;
      c1 = tc; s1 = ts;
    }
    cpx a0 = X[e][0], a1 = X[e][1];
    cpx y1 = make_float2(a0.x + a1.y, a0.y - a1.x);
    cpx y2 = make_float2(a0.x - a1.x, a0.y - a1.y);
    cpx y3 = make_float2(a0.x - a1.y, a0.y + a1.x);
    float c2 = c1 * c1 - s1 * s1, s2 = 2.f * c1 * s1;
    float c3 = c2 * c1 - s2 * s1, s3 = s2 * c1 + c2 * s1;
    X[e][0] = make_float2(a0.x + a1.x, a0.y + a1.y);
    X[e][1] = cmul(y1, c1, s1);
    X[e][2] = cmul(y2, c2, s2);
    X[e][3] = cmul(y3, c3, s3);
  }
  // stage n=4096 (q=1024): combine over e, twiddle index t
  float cb, sb;
  sc_rev(-(float)t * (1.0f / 4096.0f), cb, sb);
  float cb2 = cb * cb - sb * sb, sb2 = 2.f * cb * sb;
  float cb3 = cb2 * cb - sb2 * sb, sb3 = sb2 * cb + cb2 * sb;
  #pragma unroll
  for (int d = 0; d < 4; d++) {
    dif_core(X[0][d], X[1][d], X[2][d], X[3][d]);
    X[1][d] = cmul(X[1][d], cb, sb);
    X[2][d] = cmul(X[2][d], cb2, sb2);
    X[3][d] = cmul(X[3][d], cb3, sb3);
  }
  const int lb = t + (t >> 4);
  #pragma unroll
  for (int e = 0; e < 4; e++)
    #pragma unroll
    for (int d = 0; d < 4; d++)
      z[lb + 1088 * e + 4352 * d] = X[e][d];
}

// ---- generic forward fused pair: stages (n, n/4) ----
// p = G + jp + e*qp + d*q, G multiple of n  ->  pad(p) = lb + OE*e + OD*d
template <int n>
__device__ __forceinline__ void fwd_pair(cpx* __restrict__ z, int t) {
  constexpr int q = n >> 2;
  constexpr int qp = n >> 4;
  constexpr int OE = qp + (qp >> 4);
  constexpr int OD = q + (q >> 4);
  const int jp = t & (qp - 1);
  const int G = (t & ~(qp - 1)) << 4;
  const int lb = G + (G >> 4) + jp + (jp >> 4);
  cpx X[4][4];
  #pragma unroll
  for (int e = 0; e < 4; e++)
    #pragma unroll
    for (int d = 0; d < 4; d++)
      X[e][d] = z[lb + e * OE + d * OD];
  // stage n: combine over d, twiddle idx j = jp + e*qp, w = e^{-2pi i j/n}
  float c1, s1;
  sc_rev(-(float)jp / (float)n, c1, s1);
  #pragma unroll
  for (int e = 0; e < 4; e++) {
    if (e) {
      float tc = c1 * C16 + s1 * S16;
      float ts = s1 * C16 - c1 * S16;
      c1 = tc; s1 = ts;
    }
    dif_core(X[e][0], X[e][1], X[e][2], X[e][3]);
    float c2 = c1 * c1 - s1 * s1, s2 = 2.f * c1 * s1;
    float c3 = c2 * c1 - s2 * s1, s3 = s2 * c1 + c2 * s1;
    X[e][1] = cmul(X[e][1], c1, s1);
    X[e][2] = cmul(X[e][2], c2, s2);
    X[e][3] = cmul(X[e][3], c3, s3);
  }
  // stage n/4: combine over e, twiddle idx jp, w = e^{-2pi i jp/q}
  float cb, sb;
  sc_rev(-(float)jp / (float)q, cb, sb);
  float cb2 = cb * cb - sb * sb, sb2 = 2.f * cb * sb;
  float cb3 = cb2 * cb - sb2 * sb, sb3 = sb2 * cb + cb2 * sb;
  #pragma unroll
  for (int d = 0; d < 4; d++) {
    dif_core(X[0][d], X[1][d], X[2][d], X[3][d]);
    X[1][d] = cmul(X[1][d], cb, sb);
    X[2][d] = cmul(X[2][d], cb2, sb2);
    X[3][d] = cmul(X[3][d], cb3, sb3);
  }
  #pragma unroll
  for (int e = 0; e < 4; e++)
    #pragma unroll
    for (int d = 0; d < 4; d++)
      z[lb + e * OE + d * OD] = X[e][d];
}

// ---- forward last stage (n=4, q=1): pad(16t + 4u + v) = 17t + 4u + v ----
__device__ __forceinline__ void fwd_last(cpx* __restrict__ z, int t) {
  const int lb = 17 * t;
  #pragma unroll
  for (int u = 0; u < 4; u++) {
    cpx a0 = z[lb + 4 * u + 0];
    cpx a1 = z[lb + 4 * u + 1];
    cpx a2 = z[lb + 4 * u + 2];
    cpx a3 = z[lb + 4 * u + 3];
    dif_core(a0, a1, a2, a3);
    z[lb + 4 * u + 0] = a0;
    z[lb + 4 * u + 1] = a1;
    z[lb + 4 * u + 2] = a2;
    z[lb + 4 * u + 3] = a3;
  }
}

// ---- untangle + pointwise product (digit-reversed storage) ----
__device__ __forceinline__ void untangle(cpx* __restrict__ z, int t) {
  const float SC = 3.7252902984619141e-09f;   // 2^-28
  const float SC4 = 9.3132257461547852e-10f;  // 2^-30
  #pragma unroll
  for (int it = 0; it < 8; it++) {
    int b = t + it * TPB;
    if (b == 0) {
      cpx z0 = z[0];                      // pad(0)=0, k=0 bin
      z[0] = make_float2(z0.x * z0.y * SC, 0.f);
      cpx zm = z[2];                      // pad(2)=2, k=N/2 bin at position rev4(N/2)=2
      z[2] = make_float2(zm.x * zm.y * SC, 0.f);
    } else {
      int p = ((b >> 1) << 2) | (b & 1);
      int k = rev4_14(p);                 // 0 < k < N/2
      int pn = rev4_14(NFFT - k);
      int ap = pad(p), apn = pad(pn);
      cpx zk = z[ap];
      cpx zn = z[apn];
      float Pr = zk.x + zn.x, Pi = zk.y - zn.y;   // 2X
      float Qr = zk.x - zn.x, Qi = zk.y + zn.y;   // 2iH
      float pqr = Pr * Qr - Pi * Qi;
      float pqi = Pr * Qi + Pi * Qr;
      float Sr = pqi * SC4, Si = -pqr * SC4;      // S = -i*P*Q/4 * 2^-28
      z[ap] = make_float2(Sr, Si);
      z[apn] = make_float2(Sr, -Si);
    }
  }
}

// ---- inverse round A': stages (n=4, n=16): pad(16t + e + 4d) = 17t + e + 4d ----
__device__ __forceinline__ void inv_first(cpx* __restrict__ z, int t) {
  const int lb = 17 * t;
  cpx X[4][4];  // [e][d], p = base + e + 4d
  #pragma unroll
  for (int e = 0; e < 4; e++)
    #pragma unroll
    for (int d = 0; d < 4; d++)
      X[e][d] = z[lb + e + 4 * d];
  // stage n=4 (jA=0, no twiddle): combine over e for each d
  #pragma unroll
  for (int d = 0; d < 4; d++)
    dit_core(X[0][d], X[1][d], X[2][d], X[3][d]);
  // stage n=16: for e-slot m, twiddle inputs d by w^d, w = e^{2pi i m/16}
  dit_core(X[0][0], X[0][1], X[0][2], X[0][3]);
  X[1][1] = cmul(X[1][1], C16, S16);
  X[1][2] = cmul(X[1][2], 0.70710678118655f, 0.70710678118655f);
  X[1][3] = cmul(X[1][3], S16, C16);
  dit_core(X[1][0], X[1][1], X[1][2], X[1][3]);
  X[2][1] = cmul(X[2][1], 0.70710678118655f, 0.70710678118655f);
  X[2][2] = make_float2(-X[2][2].y, X[2][2].x);   // * i
  X[2][3] = cmul(X[2][3], -0.70710678118655f, 0.70710678118655f);
  dit_core(X[2][0], X[2][1], X[2][2], X[2][3]);
  X[3][1] = cmul(X[3][1], S16, C16);
  X[3][2] = cmul(X[3][2], -0.70710678118655f, 0.70710678118655f);
  X[3][3] = cmul(X[3][3], -C16, -S16);
  dit_core(X[3][0], X[3][1], X[3][2], X[3][3]);
  #pragma unroll
  for (int e = 0; e < 4; e++)
    #pragma unroll
    for (int d = 0; d < 4; d++)
      z[lb + e + 4 * d] = X[e][d];
}

// ---- generic inverse fused pair: stages (nA, 4*nA) ----
// p = GB + jA + e*qA + d*nA, GB multiple of 4*nA  ->  pad(p) = lb + OE*e + OD*d
template <int nA>
__device__ __forceinline__ void inv_pair(cpx* __restrict__ z, int t) {
  constexpr int qA = nA >> 2;
  constexpr int nB = nA << 2;
  constexpr int OE = qA + (qA >> 4);
  constexpr int OD = nA + (nA >> 4);
  const int jA = t & (qA - 1);
  const int GB = (t & ~(qA - 1)) << 4;
  const int lb = GB + (GB >> 4) + jA + (jA >> 4);
  cpx X[4][4];  // [e][d], p = base + e*qA + d*nA
  #pragma unroll
  for (int e = 0; e < 4; e++)
    #pragma unroll
    for (int d = 0; d < 4; d++)
      X[e][d] = z[lb + e * OE + d * OD];
  // stage nA: twiddle inputs e by w^e (w = e^{+2pi i jA/nA}), combine over e per d
  float c1, s1;
  sc_rev((float)jA / (float)nA, c1, s1);
  float c2 = c1 * c1 - s1 * s1, s2 = 2.f * c1 * s1;
  float c3 = c2 * c1 - s2 * s1, s3 = s2 * c1 + c2 * s1;
  #pragma unroll
  for (int d = 0; d < 4; d++) {
    X[1][d] = cmul(X[1][d], c1, s1);
    X[2][d] = cmul(X[2][d], c2, s2);
    X[3][d] = cmul(X[3][d], c3, s3);
    dit_core(X[0][d], X[1][d], X[2][d], X[3][d]);
  }
  // stage nB: for e-slot, angle beta_e = 2pi (jA + e*qA)/nB, twiddle inputs d
  float cb, sb;
  sc_rev((float)jA / (float)nB, cb, sb);
  #pragma unroll
  for (int e = 0; e < 4; e++) {
    if (e) {  // rotate by +2pi/16
      float tc = cb * C16 - sb * S16;
      float ts = sb * C16 + cb * S16;
      cb = tc; sb = ts;
    }
    float cb2 = cb * cb - sb * sb, sb2 = 2.f * cb * sb;
    float cb3 = cb2 * cb - sb2 * sb, sb3 = sb2 * cb + cb2 * sb;
    X[e][1] = cmul(X[e][1], cb, sb);
    X[e][2] = cmul(X[e][2], cb2, sb2);
    X[e][3] = cmul(X[e][3], cb3, sb3);
    dit_core(X[e][0], X[e][1], X[e][2], X[e][3]);
  }
  #pragma unroll
  for (int e = 0; e < 4; e++)
    #pragma unroll
    for (int d = 0; d < 4; d++)
      z[lb + e * OE + d * OD] = X[e][d];
}

// ---- inverse last stage (n=16384): only Re of outputs m=0,1 -> global ----
// p = (t + 1024u) + 4096d  ->  pad(p) = [t + (t>>4)] + 1088u + 4352d
__device__ __forceinline__ void inv_last_store(const cpx* __restrict__ z,
                                               float* __restrict__ orow, int t) {
  const int lb = t + (t >> 4);
  #pragma unroll
  for (int u = 0; u < 4; u++) {
    int j = t + 1024 * u;
    cpx a0 = z[lb + 1088 * u + 4352 * 0];
    cpx a1 = z[lb + 1088 * u + 4352 * 1];
    cpx a2 = z[lb + 1088 * u + 4352 * 2];
    cpx a3 = z[lb + 1088 * u + 4352 * 3];
    float c1, s1;
    sc_rev((float)j * (1.0f / 16384.0f), c1, s1);
    float c2 = c1 * c1 - s1 * s1, s2 = 2.f * c1 * s1;
    float c3 = c2 * c1 - s2 * s1, s3 = s2 * c1 + c2 * s1;
    float b1r = a1.x * c1 - a1.y * s1, b1i = a1.x * s1 + a1.y * c1;
    float b2r = a2.x * c2 - a2.y * s2;
    float b3r = a3.x * c3 - a3.y * s3, b3i = a3.x * s3 + a3.y * c3;
    float t0r = a0.x + b2r, t1r = a0.x - b2r;
    float t2r = b1r + b3r, t3i = b1i - b3i;
    orow[j] = t0r + t2r;             // y[j]
    orow[j + 4096] = t1r - t3i;      // y[j+4096]
  }
}

extern "C" __global__ void __launch_bounds__(TPB, 4)
fftconv_kernel(const float* __restrict__ x, const float* __restrict__ h,
               float* __restrict__ out) {
  extern __shared__ cpx z[];
  const int t = threadIdx.x;
  const long long row = blockIdx.x;
  const float* xr = x + row * LROW;
  const float* hr = h + row * LROW;

  fwd_first(xr, hr, z, t);  __syncthreads();
  fwd_pair<1024>(z, t);     __syncthreads();
  fwd_pair<64>(z, t);       __syncthreads();
  fwd_last(z, t);           __syncthreads();
  untangle(z, t);           __syncthreads();
  inv_first(z, t);          __syncthreads();
  inv_pair<64>(z, t);       __syncthreads();
  inv_pair<1024>(z, t);     __syncthreads();
  inv_last_store(z, out + row * LROW, t);
}

extern "C" void kernel_launch(void* const* d_in, const int* in_sizes, int n_in,
                              void* d_out, int out_size, void* d_ws, size_t ws_size,
                              hipStream_t stream) {
  const float* x = (const float*)d_in[0];
  const float* h = (const float*)d_in[1];
  float* out = (float*)d_out;
  const int rows = out_size / LROW;  // 4096
  const size_t lds_bytes = (size_t)LDSN * sizeof(cpx);  // 136 KiB
  (void)hipFuncSetAttribute((const void*)fftconv_kernel,
                            hipFuncAttributeMaxDynamicSharedMemorySize,
                            (int)lds_bytes);
  hipLaunchKernelGGL(fftconv_kernel, dim3(rows), dim3(TPB), lds_bytes, stream,
                     x, h, out);
}

// Round 2
// 485.176 us; speedup vs baseline: 1.1558x; 1.0401x over previous
//
#include <hip/hip_runtime.h>

#define TPB 1024
#define NFFT 16384
#define LROW 8192
#define LDSN 17408  // 16384 + 16384/16 padded complex slots (136 KiB)

// Packed FP32 complex: (re, im) in a <2 x float> so the backend emits
// v_pk_add_f32 / v_pk_mul_f32 / v_pk_fma_f32 (2x scalar FP32 issue rate).
typedef float v2f __attribute__((ext_vector_type(2)));

__device__ __forceinline__ v2f mk(float x, float y) { v2f r; r.x = x; r.y = y; return r; }
__device__ __forceinline__ v2f sp(float x) { return mk(x, x); }
__device__ __forceinline__ v2f ineg(v2f a) { return mk(a.y, -a.x); }   // -i*a
__device__ __forceinline__ v2f ipos(v2f a) { return mk(-a.y, a.x); }   // +i*a

// Twiddle in dual/splat form: cc=(c,c), ss=(s,s). Apply, square, multiply and
// rotate entirely in dual space so cmul needs no per-use broadcasts.
struct twd { v2f cc, ss; };
__device__ __forceinline__ twd mktw(float c, float s) { twd w; w.cc = sp(c); w.ss = sp(s); return w; }
__device__ __forceinline__ v2f ap(v2f a, twd w) { return a * w.cc + ipos(a) * w.ss; }
__device__ __forceinline__ twd twsq(twd w) {
  twd r; r.cc = w.cc * w.cc - w.ss * w.ss; v2f t = w.cc * w.ss; r.ss = t + t; return r;
}
__device__ __forceinline__ twd twmul(twd a, twd b) {
  twd r; r.cc = a.cc * b.cc - a.ss * b.ss; r.ss = a.ss * b.cc + a.cc * b.ss; return r;
}

#define C16 0.923879532511287f
#define S16 0.382683432365090f
#define R2H 0.70710678118655f

// rotate by -2pi/16 (forward): c'=c*C16+s*S16, s'=s*C16-c*S16
__device__ __forceinline__ twd rotf(twd w) {
  twd r; r.cc = w.cc * sp(C16) + w.ss * sp(S16); r.ss = w.ss * sp(C16) - w.cc * sp(S16); return r;
}
// rotate by +2pi/16 (inverse)
__device__ __forceinline__ twd roti(twd w) {
  twd r; r.cc = w.cc * sp(C16) - w.ss * sp(S16); r.ss = w.ss * sp(C16) + w.cc * sp(S16); return r;
}

// Padded LDS index: +1 slot per 16 complex. Injective and additive across the
// disjoint digit fields of every round: one base register + immediate offsets.
__device__ __forceinline__ int pad(int p) { return p + (p >> 4); }

// reverse 7 base-4 digits (14 bits)
__device__ __forceinline__ int rev4_14(int p) {
  unsigned r = __brev((unsigned)p) >> 18;
  return (int)(((r & 0x1555u) << 1) | ((r & 0x2AAAu) >> 1));
}

// hardware sin/cos: input in REVOLUTIONS (v_sin_f32: D = sin(S0*2pi))
__device__ __forceinline__ void sc_rev(float rev, float& c, float& s) {
  s = __builtin_amdgcn_sinf(rev);
  c = __builtin_amdgcn_cosf(rev);
}

// radix-4 DIF core (sign e^{-i}), in place, packed
__device__ __forceinline__ void dif_core(v2f& a0, v2f& a1, v2f& a2, v2f& a3) {
  v2f t0 = a0 + a2, t1 = a0 - a2;
  v2f t2 = a1 + a3, t3 = a1 - a3;
  v2f u = ineg(t3);
  a0 = t0 + t2;
  a1 = t1 + u;      // t1 - i*t3
  a2 = t0 - t2;
  a3 = t1 - u;      // t1 + i*t3
}

// radix-4 DIT core (inputs pre-twiddled, sign e^{+i}), in place, packed
__device__ __forceinline__ void dit_core(v2f& a0, v2f& a1, v2f& a2, v2f& a3) {
  v2f t0 = a0 + a2, t1 = a0 - a2;
  v2f t2 = a1 + a3, t3 = a1 - a3;
  v2f u = ineg(t3);
  a0 = t0 + t2;
  a1 = t1 - u;      // t1 + i*t3
  a2 = t0 - t2;
  a3 = t1 + u;      // t1 - i*t3
}

// ---- forward round A: global -> 2 stages in regs (n=16384, 4096) -> LDS ----
// store index p = t + 1024e + 4096d  ->  pad(p) = [t + (t>>4)] + 1088e + 4352d
__device__ __forceinline__ void fwd_first(const float* __restrict__ xr,
                                          const float* __restrict__ hr,
                                          v2f* __restrict__ z, int t) {
  v2f X[4][4];  // [e][d], p = t + 1024e + 4096d ; d=2,3 are the zero padding
  #pragma unroll
  for (int e = 0; e < 4; e++) {
    #pragma unroll
    for (int d = 0; d < 2; d++) {
      int p = t + 1024 * e + 4096 * d;
      X[e][d] = mk(xr[p], hr[p]);
    }
  }
  // stage n=16384 (q=4096): inputs d=2,3 zero => y0=a0+a1, y1=a0-i a1, y2=a0-a1, y3=a0+i a1
  float c1, s1;
  sc_rev(-(float)t * (1.0f / 16384.0f), c1, s1);
  twd w1 = mktw(c1, s1);
  #pragma unroll
  for (int e = 0; e < 4; e++) {
    if (e) w1 = rotf(w1);
    v2f a0 = X[e][0], a1 = X[e][1];
    v2f u = ineg(a1);
    v2f y1 = a0 + u;
    v2f y2 = a0 - a1;
    v2f y3 = a0 - u;
    twd w2 = twsq(w1), w3 = twmul(w2, w1);
    X[e][0] = a0 + a1;
    X[e][1] = ap(y1, w1);
    X[e][2] = ap(y2, w2);
    X[e][3] = ap(y3, w3);
  }
  // stage n=4096 (q=1024): combine over e, twiddle index t
  float cb, sb;
  sc_rev(-(float)t * (1.0f / 4096.0f), cb, sb);
  twd wb1 = mktw(cb, sb), wb2 = twsq(wb1), wb3 = twmul(wb2, wb1);
  #pragma unroll
  for (int d = 0; d < 4; d++) {
    dif_core(X[0][d], X[1][d], X[2][d], X[3][d]);
    X[1][d] = ap(X[1][d], wb1);
    X[2][d] = ap(X[2][d], wb2);
    X[3][d] = ap(X[3][d], wb3);
  }
  const int lb = t + (t >> 4);
  #pragma unroll
  for (int e = 0; e < 4; e++)
    #pragma unroll
    for (int d = 0; d < 4; d++)
      z[lb + 1088 * e + 4352 * d] = X[e][d];
}

// ---- generic forward fused pair: stages (n, n/4) ----
// p = G + jp + e*qp + d*q, G multiple of n  ->  pad(p) = lb + OE*e + OD*d
template <int n>
__device__ __forceinline__ void fwd_pair(v2f* __restrict__ z, int t) {
  constexpr int q = n >> 2;
  constexpr int qp = n >> 4;
  constexpr int OE = qp + (qp >> 4);
  constexpr int OD = q + (q >> 4);
  const int jp = t & (qp - 1);
  const int G = (t & ~(qp - 1)) << 4;
  const int lb = G + (G >> 4) + jp + (jp >> 4);
  v2f X[4][4];
  #pragma unroll
  for (int e = 0; e < 4; e++)
    #pragma unroll
    for (int d = 0; d < 4; d++)
      X[e][d] = z[lb + e * OE + d * OD];
  // stage n: combine over d, twiddle idx j = jp + e*qp, w = e^{-2pi i j/n}
  float c1, s1;
  sc_rev(-(float)jp / (float)n, c1, s1);
  twd w1 = mktw(c1, s1);
  #pragma unroll
  for (int e = 0; e < 4; e++) {
    if (e) w1 = rotf(w1);
    dif_core(X[e][0], X[e][1], X[e][2], X[e][3]);
    twd w2 = twsq(w1), w3 = twmul(w2, w1);
    X[e][1] = ap(X[e][1], w1);
    X[e][2] = ap(X[e][2], w2);
    X[e][3] = ap(X[e][3], w3);
  }
  // stage n/4: combine over e, twiddle idx jp, w = e^{-2pi i jp/q}
  float cb, sb;
  sc_rev(-(float)jp / (float)q, cb, sb);
  twd wb1 = mktw(cb, sb), wb2 = twsq(wb1), wb3 = twmul(wb2, wb1);
  #pragma unroll
  for (int d = 0; d < 4; d++) {
    dif_core(X[0][d], X[1][d], X[2][d], X[3][d]);
    X[1][d] = ap(X[1][d], wb1);
    X[2][d] = ap(X[2][d], wb2);
    X[3][d] = ap(X[3][d], wb3);
  }
  #pragma unroll
  for (int e = 0; e < 4; e++)
    #pragma unroll
    for (int d = 0; d < 4; d++)
      z[lb + e * OE + d * OD] = X[e][d];
}

// ---- forward last stage (n=4, q=1): pad(16t + 4u + v) = 17t + 4u + v ----
__device__ __forceinline__ void fwd_last(v2f* __restrict__ z, int t) {
  const int lb = 17 * t;
  #pragma unroll
  for (int u = 0; u < 4; u++) {
    v2f a0 = z[lb + 4 * u + 0];
    v2f a1 = z[lb + 4 * u + 1];
    v2f a2 = z[lb + 4 * u + 2];
    v2f a3 = z[lb + 4 * u + 3];
    dif_core(a0, a1, a2, a3);
    z[lb + 4 * u + 0] = a0;
    z[lb + 4 * u + 1] = a1;
    z[lb + 4 * u + 2] = a2;
    z[lb + 4 * u + 3] = a3;
  }
}

// ---- untangle + pointwise product (digit-reversed storage) ----
__device__ __forceinline__ void untangle(v2f* __restrict__ z, int t) {
  const float SC = 3.7252902984619141e-09f;   // 2^-28
  const float SC4 = 9.3132257461547852e-10f;  // 2^-30
  #pragma unroll
  for (int it = 0; it < 8; it++) {
    int b = t + it * TPB;
    if (b == 0) {
      v2f z0 = z[0];                      // pad(0)=0, k=0 bin
      z[0] = mk(z0.x * z0.y * SC, 0.f);
      v2f zm = z[2];                      // pad(2)=2, k=N/2 bin at rev4(N/2)=2
      z[2] = mk(zm.x * zm.y * SC, 0.f);
    } else {
      int p = ((b >> 1) << 2) | (b & 1);
      int k = rev4_14(p);                 // 0 < k < N/2
      int pn = rev4_14(NFFT - k);
      int a = pad(p), apn = pad(pn);
      v2f zk = z[a];
      v2f zn = z[apn];
      float Pr = zk.x + zn.x, Pi = zk.y - zn.y;   // 2X
      float Qr = zk.x - zn.x, Qi = zk.y + zn.y;   // 2iH
      float pqr = Pr * Qr - Pi * Qi;
      float pqi = Pr * Qi + Pi * Qr;
      float Sr = pqi * SC4, Si = -pqr * SC4;      // S = -i*P*Q/4 * 2^-28
      z[a] = mk(Sr, Si);
      z[apn] = mk(Sr, -Si);
    }
  }
}

// ---- inverse round A': stages (n=4, n=16): pad(16t + e + 4d) = 17t + e + 4d ----
__device__ __forceinline__ void inv_first(v2f* __restrict__ z, int t) {
  const int lb = 17 * t;
  v2f X[4][4];  // [e][d], p = base + e + 4d
  #pragma unroll
  for (int e = 0; e < 4; e++)
    #pragma unroll
    for (int d = 0; d < 4; d++)
      X[e][d] = z[lb + e + 4 * d];
  // stage n=4 (jA=0, no twiddle): combine over e for each d
  #pragma unroll
  for (int d = 0; d < 4; d++)
    dit_core(X[0][d], X[1][d], X[2][d], X[3][d]);
  // stage n=16: for e-slot m, twiddle inputs d by w^d, w = e^{2pi i m/16}
  const twd wA = {sp(C16), sp(S16)};
  const twd wB = {sp(R2H), sp(R2H)};
  const twd wC = {sp(S16), sp(C16)};
  const twd wD = {sp(-R2H), sp(R2H)};
  const twd wE = {sp(-C16), sp(-S16)};
  dit_core(X[0][0], X[0][1], X[0][2], X[0][3]);
  X[1][1] = ap(X[1][1], wA);
  X[1][2] = ap(X[1][2], wB);
  X[1][3] = ap(X[1][3], wC);
  dit_core(X[1][0], X[1][1], X[1][2], X[1][3]);
  X[2][1] = ap(X[2][1], wB);
  X[2][2] = ipos(X[2][2]);
  X[2][3] = ap(X[2][3], wD);
  dit_core(X[2][0], X[2][1], X[2][2], X[2][3]);
  X[3][1] = ap(X[3][1], wC);
  X[3][2] = ap(X[3][2], wD);
  X[3][3] = ap(X[3][3], wE);
  dit_core(X[3][0], X[3][1], X[3][2], X[3][3]);
  #pragma unroll
  for (int e = 0; e < 4; e++)
    #pragma unroll
    for (int d = 0; d < 4; d++)
      z[lb + e + 4 * d] = X[e][d];
}

// ---- generic inverse fused pair: stages (nA, 4*nA) ----
// p = GB + jA + e*qA + d*nA, GB multiple of 4*nA  ->  pad(p) = lb + OE*e + OD*d
template <int nA>
__device__ __forceinline__ void inv_pair(v2f* __restrict__ z, int t) {
  constexpr int qA = nA >> 2;
  constexpr int nB = nA << 2;
  constexpr int OE = qA + (qA >> 4);
  constexpr int OD = nA + (nA >> 4);
  const int jA = t & (qA - 1);
  const int GB = (t & ~(qA - 1)) << 4;
  const int lb = GB + (GB >> 4) + jA + (jA >> 4);
  v2f X[4][4];  // [e][d], p = base + e*qA + d*nA
  #pragma unroll
  for (int e = 0; e < 4; e++)
    #pragma unroll
    for (int d = 0; d < 4; d++)
      X[e][d] = z[lb + e * OE + d * OD];
  // stage nA: twiddle inputs e by w^e (w = e^{+2pi i jA/nA}), combine over e per d
  float c1, s1;
  sc_rev((float)jA / (float)nA, c1, s1);
  twd w1 = mktw(c1, s1), w2 = twsq(w1), w3 = twmul(w2, w1);
  #pragma unroll
  for (int d = 0; d < 4; d++) {
    X[1][d] = ap(X[1][d], w1);
    X[2][d] = ap(X[2][d], w2);
    X[3][d] = ap(X[3][d], w3);
    dit_core(X[0][d], X[1][d], X[2][d], X[3][d]);
  }
  // stage nB: for e-slot, angle beta_e = 2pi (jA + e*qA)/nB, twiddle inputs d
  float cb, sb;
  sc_rev((float)jA / (float)nB, cb, sb);
  twd wb = mktw(cb, sb);
  #pragma unroll
  for (int e = 0; e < 4; e++) {
    if (e) wb = roti(wb);
    twd wb2 = twsq(wb), wb3 = twmul(wb2, wb);
    X[e][1] = ap(X[e][1], wb);
    X[e][2] = ap(X[e][2], wb2);
    X[e][3] = ap(X[e][3], wb3);
    dit_core(X[e][0], X[e][1], X[e][2], X[e][3]);
  }
  #pragma unroll
  for (int e = 0; e < 4; e++)
    #pragma unroll
    for (int d = 0; d < 4; d++)
      z[lb + e * OE + d * OD] = X[e][d];
}

// ---- inverse last stage (n=16384): only Re of outputs m=0,1 -> global ----
// p = (t + 1024u) + 4096d  ->  pad(p) = [t + (t>>4)] + 1088u + 4352d
__device__ __forceinline__ void inv_last_store(const v2f* __restrict__ z,
                                               float* __restrict__ orow, int t) {
  const int lb = t + (t >> 4);
  #pragma unroll
  for (int u = 0; u < 4; u++) {
    int j = t + 1024 * u;
    v2f a0 = z[lb + 1088 * u + 4352 * 0];
    v2f a1 = z[lb + 1088 * u + 4352 * 1];
    v2f a2 = z[lb + 1088 * u + 4352 * 2];
    v2f a3 = z[lb + 1088 * u + 4352 * 3];
    float c1, s1;
    sc_rev((float)j * (1.0f / 16384.0f), c1, s1);
    float c2 = c1 * c1 - s1 * s1, s2 = 2.f * c1 * s1;
    float c3 = c2 * c1 - s2 * s1, s3 = s2 * c1 + c2 * s1;
    float b1r = a1.x * c1 - a1.y * s1, b1i = a1.x * s1 + a1.y * c1;
    float b2r = a2.x * c2 - a2.y * s2;
    float b3r = a3.x * c3 - a3.y * s3, b3i = a3.x * s3 + a3.y * c3;
    float t0r = a0.x + b2r, t1r = a0.x - b2r;
    float t2r = b1r + b3r, t3i = b1i - b3i;
    orow[j] = t0r + t2r;             // y[j]
    orow[j + 4096] = t1r - t3i;      // y[j+4096]
  }
}

extern "C" __global__ void __launch_bounds__(TPB, 4)
fftconv_kernel(const float* __restrict__ x, const float* __restrict__ h,
               float* __restrict__ out) {
  extern __shared__ v2f z[];
  const int t = threadIdx.x;
  const long long row = blockIdx.x;
  const float* xr = x + row * LROW;
  const float* hr = h + row * LROW;

  fwd_first(xr, hr, z, t);  __syncthreads();
  fwd_pair<1024>(z, t);     __syncthreads();
  fwd_pair<64>(z, t);       __syncthreads();
  fwd_last(z, t);           __syncthreads();
  untangle(z, t);           __syncthreads();
  inv_first(z, t);          __syncthreads();
  inv_pair<64>(z, t);       __syncthreads();
  inv_pair<1024>(z, t);     __syncthreads();
  inv_last_store(z, out + row * LROW, t);
}

extern "C" void kernel_launch(void* const* d_in, const int* in_sizes, int n_in,
                              void* d_out, int out_size, void* d_ws, size_t ws_size,
                              hipStream_t stream) {
  const float* x = (const float*)d_in[0];
  const float* h = (const float*)d_in[1];
  float* out = (float*)d_out;
  const int rows = out_size / LROW;  // 4096
  const size_t lds_bytes = (size_t)LDSN * sizeof(v2f);  // 136 KiB
  (void)hipFuncSetAttribute((const void*)fftconv_kernel,
                            hipFuncAttributeMaxDynamicSharedMemorySize,
                            (int)lds_bytes);
  hipLaunchKernelGGL(fftconv_kernel, dim3(rows), dim3(TPB), lds_bytes, stream,
                     x, h, out);
}

// Round 3
// 453.451 us; speedup vs baseline: 1.2366x; 1.0700x over previous
//
#include <hip/hip_runtime.h>

#define TPB 1024
#define NFFT 16384
#define LROW 8192
#define LDSN 17408  // 16384 + 16384/16 padded complex slots (136 KiB)

// Packed FP32 complex: (re, im) in a <2 x float> so the backend emits
// v_pk_add_f32 / v_pk_mul_f32 / v_pk_fma_f32 (2x scalar FP32 issue rate).
typedef float v2f __attribute__((ext_vector_type(2)));

__device__ __forceinline__ v2f mk(float x, float y) { v2f r; r.x = x; r.y = y; return r; }
__device__ __forceinline__ v2f sp(float x) { return mk(x, x); }
__device__ __forceinline__ v2f ineg(v2f a) { return mk(a.y, -a.x); }   // -i*a
__device__ __forceinline__ v2f ipos(v2f a) { return mk(-a.y, a.x); }   // +i*a

// Twiddle in dual/splat form: cc=(c,c), ss=(s,s). Apply, square, multiply and
// rotate entirely in dual space so cmul needs no per-use broadcasts.
struct twd { v2f cc, ss; };
__device__ __forceinline__ twd mktw(float c, float s) { twd w; w.cc = sp(c); w.ss = sp(s); return w; }
__device__ __forceinline__ v2f ap(v2f a, twd w) { return a * w.cc + ipos(a) * w.ss; }
__device__ __forceinline__ twd twsq(twd w) {
  twd r; r.cc = w.cc * w.cc - w.ss * w.ss; v2f t = w.cc * w.ss; r.ss = t + t; return r;
}
__device__ __forceinline__ twd twmul(twd a, twd b) {
  twd r; r.cc = a.cc * b.cc - a.ss * b.ss; r.ss = a.ss * b.cc + a.cc * b.ss; return r;
}

#define C16 0.923879532511287f
#define S16 0.382683432365090f
#define R2H 0.70710678118655f

// rotate by -2pi/16 (forward): c'=c*C16+s*S16, s'=s*C16-c*S16
__device__ __forceinline__ twd rotf(twd w) {
  twd r; r.cc = w.cc * sp(C16) + w.ss * sp(S16); r.ss = w.ss * sp(C16) - w.cc * sp(S16); return r;
}
// rotate by +2pi/16 (inverse)
__device__ __forceinline__ twd roti(twd w) {
  twd r; r.cc = w.cc * sp(C16) - w.ss * sp(S16); r.ss = w.ss * sp(C16) + w.cc * sp(S16); return r;
}

// hardware sin/cos: input in REVOLUTIONS (v_sin_f32: D = sin(S0*2pi))
__device__ __forceinline__ void sc_rev(float rev, float& c, float& s) {
  s = __builtin_amdgcn_sinf(rev);
  c = __builtin_amdgcn_cosf(rev);
}

// radix-4 DIF core (sign e^{-i}), in place, packed
__device__ __forceinline__ void dif_core(v2f& a0, v2f& a1, v2f& a2, v2f& a3) {
  v2f t0 = a0 + a2, t1 = a0 - a2;
  v2f t2 = a1 + a3, t3 = a1 - a3;
  v2f u = ineg(t3);
  a0 = t0 + t2;
  a1 = t1 + u;      // t1 - i*t3
  a2 = t0 - t2;
  a3 = t1 - u;      // t1 + i*t3
}

// radix-4 DIT core (inputs pre-twiddled, sign e^{+i}), in place, packed
__device__ __forceinline__ void dit_core(v2f& a0, v2f& a1, v2f& a2, v2f& a3) {
  v2f t0 = a0 + a2, t1 = a0 - a2;
  v2f t2 = a1 + a3, t3 = a1 - a3;
  v2f u = ineg(t3);
  a0 = t0 + t2;
  a1 = t1 - u;      // t1 + i*t3
  a2 = t0 - t2;
  a3 = t1 + u;      // t1 - i*t3
}

// ---- forward round A: global -> 2 stages in regs (n=16384, 4096) -> LDS ----
// store index p = t + 1024e + 4096d  ->  pad(p) = [t + (t>>4)] + 1088e + 4352d
__device__ __forceinline__ void fwd_first(const float* __restrict__ xr,
                                          const float* __restrict__ hr,
                                          v2f* __restrict__ z, int t) {
  v2f X[4][4];  // [e][d], p = t + 1024e + 4096d ; d=2,3 are the zero padding
  #pragma unroll
  for (int e = 0; e < 4; e++) {
    #pragma unroll
    for (int d = 0; d < 2; d++) {
      int p = t + 1024 * e + 4096 * d;
      X[e][d] = mk(xr[p], hr[p]);
    }
  }
  // stage n=16384 (q=4096): inputs d=2,3 zero => y0=a0+a1, y1=a0-i a1, y2=a0-a1, y3=a0+i a1
  float c1, s1;
  sc_rev(-(float)t * (1.0f / 16384.0f), c1, s1);
  twd w1 = mktw(c1, s1);
  #pragma unroll
  for (int e = 0; e < 4; e++) {
    if (e) w1 = rotf(w1);
    v2f a0 = X[e][0], a1 = X[e][1];
    v2f u = ineg(a1);
    v2f y1 = a0 + u;
    v2f y2 = a0 - a1;
    v2f y3 = a0 - u;
    twd w2 = twsq(w1), w3 = twmul(w2, w1);
    X[e][0] = a0 + a1;
    X[e][1] = ap(y1, w1);
    X[e][2] = ap(y2, w2);
    X[e][3] = ap(y3, w3);
  }
  // stage n=4096 (q=1024): combine over e, twiddle index t
  float cb, sb;
  sc_rev(-(float)t * (1.0f / 4096.0f), cb, sb);
  twd wb1 = mktw(cb, sb), wb2 = twsq(wb1), wb3 = twmul(wb2, wb1);
  #pragma unroll
  for (int d = 0; d < 4; d++) {
    dif_core(X[0][d], X[1][d], X[2][d], X[3][d]);
    X[1][d] = ap(X[1][d], wb1);
    X[2][d] = ap(X[2][d], wb2);
    X[3][d] = ap(X[3][d], wb3);
  }
  const int lb = t + (t >> 4);
  #pragma unroll
  for (int e = 0; e < 4; e++)
    #pragma unroll
    for (int d = 0; d < 4; d++)
      z[lb + 1088 * e + 4352 * d] = X[e][d];
}

// ---- generic forward fused pair: stages (n, n/4) ----
// p = G + jp + e*qp + d*q, G multiple of n  ->  pad(p) = lb + OE*e + OD*d
template <int n>
__device__ __forceinline__ void fwd_pair(v2f* __restrict__ z, int t) {
  constexpr int q = n >> 2;
  constexpr int qp = n >> 4;
  constexpr int OE = qp + (qp >> 4);
  constexpr int OD = q + (q >> 4);
  const int jp = t & (qp - 1);
  const int G = (t & ~(qp - 1)) << 4;
  const int lb = G + (G >> 4) + jp + (jp >> 4);
  v2f X[4][4];
  #pragma unroll
  for (int e = 0; e < 4; e++)
    #pragma unroll
    for (int d = 0; d < 4; d++)
      X[e][d] = z[lb + e * OE + d * OD];
  // stage n: combine over d, twiddle idx j = jp + e*qp, w = e^{-2pi i j/n}
  float c1, s1;
  sc_rev(-(float)jp / (float)n, c1, s1);
  twd w1 = mktw(c1, s1);
  #pragma unroll
  for (int e = 0; e < 4; e++) {
    if (e) w1 = rotf(w1);
    dif_core(X[e][0], X[e][1], X[e][2], X[e][3]);
    twd w2 = twsq(w1), w3 = twmul(w2, w1);
    X[e][1] = ap(X[e][1], w1);
    X[e][2] = ap(X[e][2], w2);
    X[e][3] = ap(X[e][3], w3);
  }
  // stage n/4: combine over e, twiddle idx jp, w = e^{-2pi i jp/q}
  float cb, sb;
  sc_rev(-(float)jp / (float)q, cb, sb);
  twd wb1 = mktw(cb, sb), wb2 = twsq(wb1), wb3 = twmul(wb2, wb1);
  #pragma unroll
  for (int d = 0; d < 4; d++) {
    dif_core(X[0][d], X[1][d], X[2][d], X[3][d]);
    X[1][d] = ap(X[1][d], wb1);
    X[2][d] = ap(X[2][d], wb2);
    X[3][d] = ap(X[3][d], wb3);
  }
  #pragma unroll
  for (int e = 0; e < 4; e++)
    #pragma unroll
    for (int d = 0; d < 4; d++)
      z[lb + e * OE + d * OD] = X[e][d];
}

// ---- fused middle round: fwd last stage (n=4) + pointwise square + inverse
// stages (n=4, n=16), all on the 16 contiguous slots z[17t .. 17t+15].
// Identity: with Z = FFT(x + i h), G = X*H satisfies G(k) = W(k) + conj(W(N-k))
// where W(k) = -i Z(k)^2 / 4 is LOCAL per bin; IDFT then gives
// y(n) = 2 Re{IDFT[W]}(n) — Im is discarded by inv_last_store anyway.
// So: square in place, no conjugate pairing, no digit-reversal, no edge cases.
// Scale: W = -i Z^2 * 2^-29  =>  (2^-28 * x * y,  2^-29 * (y^2 - x^2)).
__device__ __forceinline__ void mid_round(v2f* __restrict__ z, int t) {
  const int lb = 17 * t;
  v2f R[4][4];  // R[v][u] = z[lb + 4u + v]
  #pragma unroll
  for (int u = 0; u < 4; u++)
    #pragma unroll
    for (int v = 0; v < 4; v++)
      R[v][u] = z[lb + 4 * u + v];
  // forward last stage (n=4, q=1, no twiddles): DIF over v within each group u
  #pragma unroll
  for (int u = 0; u < 4; u++)
    dif_core(R[0][u], R[1][u], R[2][u], R[3][u]);
  // pointwise: W = -i * Z^2 * 2^-29
  const float s  = 1.8626451492309570e-09f;  // 2^-29
  const float s2 = 3.7252902984619141e-09f;  // 2^-28
  #pragma unroll
  for (int v = 0; v < 4; v++)
    #pragma unroll
    for (int u = 0; u < 4; u++) {
      v2f a = R[v][u];
      R[v][u] = mk(s2 * a.x * a.y, s * (a.y * a.y - a.x * a.x));
    }
  // inverse stage n=4 (jA=0, no twiddles): DIT over v within each group u
  #pragma unroll
  for (int u = 0; u < 4; u++)
    dit_core(R[0][u], R[1][u], R[2][u], R[3][u]);
  // inverse stage n=16: for v-slot m, twiddle inputs u by w^u, w = e^{2pi i m/16}
  const twd wA = {sp(C16), sp(S16)};
  const twd wB = {sp(R2H), sp(R2H)};
  const twd wC = {sp(S16), sp(C16)};
  const twd wD = {sp(-R2H), sp(R2H)};
  const twd wE = {sp(-C16), sp(-S16)};
  dit_core(R[0][0], R[0][1], R[0][2], R[0][3]);
  R[1][1] = ap(R[1][1], wA);
  R[1][2] = ap(R[1][2], wB);
  R[1][3] = ap(R[1][3], wC);
  dit_core(R[1][0], R[1][1], R[1][2], R[1][3]);
  R[2][1] = ap(R[2][1], wB);
  R[2][2] = ipos(R[2][2]);
  R[2][3] = ap(R[2][3], wD);
  dit_core(R[2][0], R[2][1], R[2][2], R[2][3]);
  R[3][1] = ap(R[3][1], wC);
  R[3][2] = ap(R[3][2], wD);
  R[3][3] = ap(R[3][3], wE);
  dit_core(R[3][0], R[3][1], R[3][2], R[3][3]);
  #pragma unroll
  for (int u = 0; u < 4; u++)
    #pragma unroll
    for (int v = 0; v < 4; v++)
      z[lb + 4 * u + v] = R[v][u];
}

// ---- generic inverse fused pair: stages (nA, 4*nA) ----
// p = GB + jA + e*qA + d*nA, GB multiple of 4*nA  ->  pad(p) = lb + OE*e + OD*d
template <int nA>
__device__ __forceinline__ void inv_pair(v2f* __restrict__ z, int t) {
  constexpr int qA = nA >> 2;
  constexpr int nB = nA << 2;
  constexpr int OE = qA + (qA >> 4);
  constexpr int OD = nA + (nA >> 4);
  const int jA = t & (qA - 1);
  const int GB = (t & ~(qA - 1)) << 4;
  const int lb = GB + (GB >> 4) + jA + (jA >> 4);
  v2f X[4][4];  // [e][d], p = base + e*qA + d*nA
  #pragma unroll
  for (int e = 0; e < 4; e++)
    #pragma unroll
    for (int d = 0; d < 4; d++)
      X[e][d] = z[lb + e * OE + d * OD];
  // stage nA: twiddle inputs e by w^e (w = e^{+2pi i jA/nA}), combine over e per d
  float c1, s1;
  sc_rev((float)jA / (float)nA, c1, s1);
  twd w1 = mktw(c1, s1), w2 = twsq(w1), w3 = twmul(w2, w1);
  #pragma unroll
  for (int d = 0; d < 4; d++) {
    X[1][d] = ap(X[1][d], w1);
    X[2][d] = ap(X[2][d], w2);
    X[3][d] = ap(X[3][d], w3);
    dit_core(X[0][d], X[1][d], X[2][d], X[3][d]);
  }
  // stage nB: for e-slot, angle beta_e = 2pi (jA + e*qA)/nB, twiddle inputs d
  float cb, sb;
  sc_rev((float)jA / (float)nB, cb, sb);
  twd wb = mktw(cb, sb);
  #pragma unroll
  for (int e = 0; e < 4; e++) {
    if (e) wb = roti(wb);
    twd wb2 = twsq(wb), wb3 = twmul(wb2, wb);
    X[e][1] = ap(X[e][1], wb);
    X[e][2] = ap(X[e][2], wb2);
    X[e][3] = ap(X[e][3], wb3);
    dit_core(X[e][0], X[e][1], X[e][2], X[e][3]);
  }
  #pragma unroll
  for (int e = 0; e < 4; e++)
    #pragma unroll
    for (int d = 0; d < 4; d++)
      z[lb + e * OE + d * OD] = X[e][d];
}

// ---- inverse last stage (n=16384): only Re of outputs m=0,1 -> global ----
// p = (t + 1024u) + 4096d  ->  pad(p) = [t + (t>>4)] + 1088u + 4352d
__device__ __forceinline__ void inv_last_store(const v2f* __restrict__ z,
                                               float* __restrict__ orow, int t) {
  const int lb = t + (t >> 4);
  #pragma unroll
  for (int u = 0; u < 4; u++) {
    int j = t + 1024 * u;
    v2f a0 = z[lb + 1088 * u + 4352 * 0];
    v2f a1 = z[lb + 1088 * u + 4352 * 1];
    v2f a2 = z[lb + 1088 * u + 4352 * 2];
    v2f a3 = z[lb + 1088 * u + 4352 * 3];
    float c1, s1;
    sc_rev((float)j * (1.0f / 16384.0f), c1, s1);
    float c2 = c1 * c1 - s1 * s1, s2 = 2.f * c1 * s1;
    float c3 = c2 * c1 - s2 * s1, s3 = s2 * c1 + c2 * s1;
    float b1r = a1.x * c1 - a1.y * s1, b1i = a1.x * s1 + a1.y * c1;
    float b2r = a2.x * c2 - a2.y * s2;
    float b3r = a3.x * c3 - a3.y * s3, b3i = a3.x * s3 + a3.y * c3;
    float t0r = a0.x + b2r, t1r = a0.x - b2r;
    float t2r = b1r + b3r, t3i = b1i - b3i;
    orow[j] = t0r + t2r;             // y[j]
    orow[j + 4096] = t1r - t3i;      // y[j+4096]
  }
}

extern "C" __global__ void __launch_bounds__(TPB, 4)
fftconv_kernel(const float* __restrict__ x, const float* __restrict__ h,
               float* __restrict__ out) {
  extern __shared__ v2f z[];
  const int t = threadIdx.x;
  const long long row = blockIdx.x;
  const float* xr = x + row * LROW;
  const float* hr = h + row * LROW;

  fwd_first(xr, hr, z, t);  __syncthreads();
  fwd_pair<1024>(z, t);     __syncthreads();
  fwd_pair<64>(z, t);       __syncthreads();
  mid_round(z, t);          __syncthreads();
  inv_pair<64>(z, t);       __syncthreads();
  inv_pair<1024>(z, t);     __syncthreads();
  inv_last_store(z, out + row * LROW, t);
}

extern "C" void kernel_launch(void* const* d_in, const int* in_sizes, int n_in,
                              void* d_out, int out_size, void* d_ws, size_t ws_size,
                              hipStream_t stream) {
  const float* x = (const float*)d_in[0];
  const float* h = (const float*)d_in[1];
  float* out = (float*)d_out;
  const int rows = out_size / LROW;  // 4096
  const size_t lds_bytes = (size_t)LDSN * sizeof(v2f);  // 136 KiB
  (void)hipFuncSetAttribute((const void*)fftconv_kernel,
                            hipFuncAttributeMaxDynamicSharedMemorySize,
                            (int)lds_bytes);
  hipLaunchKernelGGL(fftconv_kernel, dim3(rows), dim3(TPB), lds_bytes, stream,
                     x, h, out);
}